// Round 13
// baseline (258.386 us; speedup 1.0000x reference)
//
#include <hip/hip_runtime.h>
#include <hip/hip_fp16.h>

#define D 128
#define NB 256          // counting-sort chunks == grid blocks of preprocess
#define Q 8             // quarters for the b-dimension scan
#define BQ (NB / Q)     // blocks per quarter = 32
#define NBINS_MAX 10016 // max nodes supported by LDS histogram (~40 KB)
#define GM 32           // gemm rows per block

// ---------------- all-to-all grid barrier (monotonic counter) ----------------
// All 256 blocks co-resident by construction (80KB LDS -> 2/CU packable; grid == CU count).
// Device-scope atomicAdd + threadfence = cross-XCD visibility (G16).
__device__ __forceinline__ void gridbar(int* bar, int phase) {
    __syncthreads();
    if (threadIdx.x == 0) {
        __threadfence();
        atomicAdd(bar, 1);
        int target = NB * (phase + 1);
        while (atomicAdd(bar, 0) < target) { __builtin_amdgcn_s_sleep(2); }
        __threadfence();
    }
    __syncthreads();
}

// ---------------- FUSED preprocess: cast+hist | colscan | finalize | scan | fill ----------------
// One kernel, 5 grid barriers, 256 blocks x 256 threads. Integer pipeline is
// bit-identical to the R12 4-kernel chain -> sorted[] identical -> absmax locked
// at 2.441e-4 (built-in correctness check).
__global__ __launch_bounds__(256) void preprocess_kernel(
        const int* __restrict__ src, const int* __restrict__ dst,
        const float* __restrict__ x, __half* __restrict__ xh, int total4,
        const float* __restrict__ ew,
        int* __restrict__ pd, unsigned short* __restrict__ ps,
        int* __restrict__ qtot_d, int* __restrict__ qtot_s,
        int* __restrict__ row_start, float* __restrict__ norm_src, float* __restrict__ norm_dst,
        int2* __restrict__ sorted,
        int* __restrict__ bar, int* __restrict__ part_g, int* __restrict__ base_g,
        int E, int n, int nb4) {
    __shared__ __align__(16) int hd[NBINS_MAX];   // hist dst | P2/P4 reduce+scan buf | fill cursor
    __shared__ __align__(16) int hs[NBINS_MAX];   // hist src | P2/P4 deg slice (1024 ints)
    int b = blockIdx.x, t = threadIdx.x;
    int chunk = (E + NB - 1) / NB;
    int e0 = b * chunk, e1 = min(e0 + chunk, E);
    int nf = n >> 2;

    // ---- P0: cast x->fp16 (grid-stride) + per-chunk LDS histograms ----
    for (int i = b * 256 + t; i < total4; i += NB * 256) {
        float4 v = *(const float4*)(x + (size_t)i * 4);
        __half2 a = __floats2half2_rn(v.x, v.y);
        __half2 c = __floats2half2_rn(v.z, v.w);
        *(__half2*)(xh + (size_t)i * 4) = a;
        *(__half2*)(xh + (size_t)i * 4 + 2) = c;
    }
    int nq = (n + 3) >> 2;
    for (int i = t; i < nq; i += 256) {
        *(int4*)(&hd[i * 4]) = make_int4(0, 0, 0, 0);
        *(int4*)(&hs[i * 4]) = make_int4(0, 0, 0, 0);
    }
    __syncthreads();
    for (int e = e0 + t; e < e1; e += 256) {
        atomicAdd(&hd[dst[e]], 1);
        atomicAdd(&hs[src[e]], 1);
    }
    __syncthreads();
    for (int i = t; i < nf; i += 256) {
        int4 h = *(const int4*)(&hd[i * 4]);
        *(int4*)(pd + (size_t)b * n + i * 4) = h;
        int4 s = *(const int4*)(&hs[i * 4]);
        uint2 u;
        u.x = (unsigned)(s.x & 0xFFFF) | ((unsigned)(s.y & 0xFFFF) << 16);
        u.y = (unsigned)(s.z & 0xFFFF) | ((unsigned)(s.w & 0xFFFF) << 16);
        *(uint2*)(ps + (size_t)b * n + i * 4) = u;
    }
    for (int i = nf * 4 + t; i < n; i += 256) {
        pd[(size_t)b * n + i] = hd[i];
        ps[(size_t)b * n + i] = (unsigned short)hs[i];
    }
    gridbar(bar, 0);

    // ---- P1: within-quarter column scan (nb4*Q block-tasks) ----
    if (b < nb4 * Q) {
        int gx = b % nb4;
        int q  = b / nb4;
        int bin4 = (gx * 256 + t) * 4;
        if (bin4 < n) {
            int b0 = q * BQ;
            if (bin4 + 3 < n) {
                int4 run = make_int4(0, 0, 0, 0);
                int4 ssum = make_int4(0, 0, 0, 0);
#pragma unroll 8
                for (int j = 0; j < BQ; ++j) {
                    size_t idx = (size_t)(b0 + j) * n + bin4;
                    int4 v = *(const int4*)(pd + idx);
                    *(int4*)(pd + idx) = run;
                    run.x += v.x; run.y += v.y; run.z += v.z; run.w += v.w;
                    uint2 u = *(const uint2*)(ps + idx);
                    ssum.x += (int)(u.x & 0xFFFF); ssum.y += (int)(u.x >> 16);
                    ssum.z += (int)(u.y & 0xFFFF); ssum.w += (int)(u.y >> 16);
                }
                *(int4*)(qtot_d + (size_t)q * n + bin4) = run;
                *(int4*)(qtot_s + (size_t)q * n + bin4) = ssum;
            } else {
                for (int bin = bin4; bin < n; ++bin) {
                    int run = 0, ssum = 0;
                    for (int j = 0; j < BQ; ++j) {
                        size_t idx = (size_t)(b0 + j) * n + bin;
                        int v = pd[idx];
                        pd[idx] = run;
                        run += v;
                        ssum += (int)ps[idx];
                    }
                    qtot_d[(size_t)q * n + bin] = run;
                    qtot_s[(size_t)q * n + bin] = ssum;
                }
            }
        }
    }
    gridbar(bar, 1);

    // ---- P2: finalize (qbase prefix, deg->LDS, norms) + block partial sum; blocks 0..nb4-1 ----
    int* degL = hs;            // this block's 1024 deg values
    int* redL = hd;            // 256-wide reduce/scan buffer
    if (b < nb4) {
        int l4 = t * 4;
        int b4 = b * 1024 + l4;
        int cnt = (b4 < n) ? min(4, n - b4) : 0;
        int tot = 0;
        if (cnt == 4) {
            int4 qv[Q];
#pragma unroll
            for (int q = 0; q < Q; ++q) qv[q] = *(const int4*)(qtot_d + (size_t)q * n + b4);
            int4 run = make_int4(0, 0, 0, 0);
#pragma unroll
            for (int q = 0; q < Q; ++q) {
                *(int4*)(qtot_d + (size_t)q * n + b4) = run;
                run.x += qv[q].x; run.y += qv[q].y; run.z += qv[q].z; run.w += qv[q].w;
            }
            *(int4*)(&degL[l4]) = run;
            norm_dst[b4 + 0] = rsqrtf(fmaxf((float)run.x, 1.0f));
            norm_dst[b4 + 1] = rsqrtf(fmaxf((float)run.y, 1.0f));
            norm_dst[b4 + 2] = rsqrtf(fmaxf((float)run.z, 1.0f));
            norm_dst[b4 + 3] = rsqrtf(fmaxf((float)run.w, 1.0f));
            int4 st = make_int4(0, 0, 0, 0);
#pragma unroll
            for (int q = 0; q < Q; ++q) {
                int4 v = *(const int4*)(qtot_s + (size_t)q * n + b4);
                st.x += v.x; st.y += v.y; st.z += v.z; st.w += v.w;
            }
            norm_src[b4 + 0] = rsqrtf(fmaxf((float)st.x, 1.0f));
            norm_src[b4 + 1] = rsqrtf(fmaxf((float)st.y, 1.0f));
            norm_src[b4 + 2] = rsqrtf(fmaxf((float)st.z, 1.0f));
            norm_src[b4 + 3] = rsqrtf(fmaxf((float)st.w, 1.0f));
            tot = run.x + run.y + run.z + run.w;
        } else if (cnt > 0) {
            for (int j = 0; j < cnt; ++j) {
                int bin = b4 + j;
                int run = 0;
                for (int q = 0; q < Q; ++q) {
                    size_t i = (size_t)q * n + bin;
                    int v = qtot_d[i];
                    qtot_d[i] = run;
                    run += v;
                }
                degL[l4 + j] = run;
                tot += run;
                norm_dst[bin] = rsqrtf(fmaxf((float)run, 1.0f));
                int tt = 0;
                for (int q = 0; q < Q; ++q) tt += qtot_s[(size_t)q * n + bin];
                norm_src[bin] = rsqrtf(fmaxf((float)tt, 1.0f));
            }
        }
        redL[t] = tot;
        __syncthreads();
        for (int off = 128; off > 0; off >>= 1) {
            if (t < off) redL[t] += redL[t + off];
            __syncthreads();
        }
        if (t == 0) part_g[b] = redL[0];
    }
    gridbar(bar, 2);

    // ---- P3: block 0 scans the nb4 partials ----
    if (b == 0 && t == 0) {
        int running = 0;
        for (int i = 0; i < nb4; ++i) {
            base_g[i] = running;
            running += part_g[i];
        }
        row_start[n] = running;   // total E
    }
    gridbar(bar, 3);

    // ---- P4: blocks 0..nb4-1 write row_start slice from degL + base ----
    if (b < nb4) {
        int l4 = t * 4;
        int b4 = b * 1024 + l4;
        int cnt = (b4 < n) ? min(4, n - b4) : 0;
        int tot = 0;
        for (int j = 0; j < cnt; ++j) tot += degL[l4 + j];
        redL[t] = tot;
        __syncthreads();
        for (int off = 1; off < 256; off <<= 1) {
            int v = (t >= off) ? redL[t - off] : 0;
            __syncthreads();
            if (t >= off) redL[t] += v;
            __syncthreads();
        }
        int run = base_g[b] + redL[t] - tot;
        for (int j = 0; j < cnt; ++j) {
            row_start[b4 + j] = run;
            run += degL[l4 + j];
        }
    }
    gridbar(bar, 4);

    // ---- P5: CSR fill (all blocks); cursor reuses hd ----
    {
        int* cursor = hd;
        int q = b / BQ;
        for (int i = t; i < nf; i += 256) {
            int4 r = *(const int4*)(row_start + i * 4);
            int4 a = *(const int4*)(qtot_d + (size_t)q * n + i * 4);
            int4 c = *(const int4*)(pd + (size_t)b * n + i * 4);
            *(int4*)(&cursor[i * 4]) = make_int4(r.x + a.x + c.x, r.y + a.y + c.y,
                                                 r.z + a.z + c.z, r.w + a.w + c.w);
        }
        for (int i = nf * 4 + t; i < n; i += 256)
            cursor[i] = row_start[i] + qtot_d[(size_t)q * n + i] + pd[(size_t)b * n + i];
        __syncthreads();
        for (int e = e0 + t; e < e1; e += 256) {
            int d = dst[e];
            int slot = atomicAdd(&cursor[d], 1);
            int s = src[e];
            int2 rec;
            rec.x = s;
            rec.y = __float_as_int(ew[e] * norm_src[s]);
            sorted[slot] = rec;
        }
    }
}

// ---------------- full-row aggregation: one wave per node, half2 per lane ----------------
// EPI=0: raw fp32 store (feeds gemmfused). EPI=1: final epilogue at store.
template <int EPI>
__global__ __launch_bounds__(256) void agg_kernel(const __half* __restrict__ h, const int* __restrict__ row_start,
                                                  const int2* __restrict__ sorted, float* __restrict__ out,
                                                  const float* __restrict__ norm_dst, const float* __restrict__ bias,
                                                  int n) {
    int wave = threadIdx.x >> 6;
    int lane = threadIdx.x & 63;
    int node = blockIdx.x * 4 + wave;
    if (node >= n) return;
    const __half2* hc = (const __half2*)h + lane;   // row r at hc[r<<6]
    int beg = __builtin_amdgcn_readfirstlane(row_start[node]);
    int end = __builtin_amdgcn_readfirstlane(row_start[node + 1]);
    float accx = 0.f, accy = 0.f;
    int s = beg;
    if (s < end && (s & 1)) {
        int2 rr = sorted[s];
        float w = __int_as_float(rr.y);
        float2 f = __half22float2(hc[(size_t)rr.x << 6]);
        accx = fmaf(w, f.x, accx); accy = fmaf(w, f.y, accy);
        ++s;
    }
    int4 p0, p1, p2, p3, p4, p5, p6, p7;
    if (s + 16 <= end) {
        p0 = *(const int4*)(sorted + s);
        p1 = *(const int4*)(sorted + s + 2);
        p2 = *(const int4*)(sorted + s + 4);
        p3 = *(const int4*)(sorted + s + 6);
        p4 = *(const int4*)(sorted + s + 8);
        p5 = *(const int4*)(sorted + s + 10);
        p6 = *(const int4*)(sorted + s + 12);
        p7 = *(const int4*)(sorted + s + 14);
    }
    for (; s + 32 <= end; s += 16) {
        int4 q0 = *(const int4*)(sorted + s + 16);
        int4 q1 = *(const int4*)(sorted + s + 18);
        int4 q2 = *(const int4*)(sorted + s + 20);
        int4 q3 = *(const int4*)(sorted + s + 22);
        int4 q4 = *(const int4*)(sorted + s + 24);
        int4 q5 = *(const int4*)(sorted + s + 26);
        int4 q6 = *(const int4*)(sorted + s + 28);
        int4 q7 = *(const int4*)(sorted + s + 30);
        __half2 x0  = hc[(size_t)p0.x << 6];
        __half2 x1  = hc[(size_t)p0.z << 6];
        __half2 x2  = hc[(size_t)p1.x << 6];
        __half2 x3  = hc[(size_t)p1.z << 6];
        __half2 x4  = hc[(size_t)p2.x << 6];
        __half2 x5  = hc[(size_t)p2.z << 6];
        __half2 x6  = hc[(size_t)p3.x << 6];
        __half2 x7  = hc[(size_t)p3.z << 6];
        __half2 x8  = hc[(size_t)p4.x << 6];
        __half2 x9  = hc[(size_t)p4.z << 6];
        __half2 x10 = hc[(size_t)p5.x << 6];
        __half2 x11 = hc[(size_t)p5.z << 6];
        __half2 x12 = hc[(size_t)p6.x << 6];
        __half2 x13 = hc[(size_t)p6.z << 6];
        __half2 x14 = hc[(size_t)p7.x << 6];
        __half2 x15 = hc[(size_t)p7.z << 6];
        float2 f;
        f = __half22float2(x0);  accx = fmaf(__int_as_float(p0.y), f.x, accx); accy = fmaf(__int_as_float(p0.y), f.y, accy);
        f = __half22float2(x1);  accx = fmaf(__int_as_float(p0.w), f.x, accx); accy = fmaf(__int_as_float(p0.w), f.y, accy);
        f = __half22float2(x2);  accx = fmaf(__int_as_float(p1.y), f.x, accx); accy = fmaf(__int_as_float(p1.y), f.y, accy);
        f = __half22float2(x3);  accx = fmaf(__int_as_float(p1.w), f.x, accx); accy = fmaf(__int_as_float(p1.w), f.y, accy);
        f = __half22float2(x4);  accx = fmaf(__int_as_float(p2.y), f.x, accx); accy = fmaf(__int_as_float(p2.y), f.y, accy);
        f = __half22float2(x5);  accx = fmaf(__int_as_float(p2.w), f.x, accx); accy = fmaf(__int_as_float(p2.w), f.y, accy);
        f = __half22float2(x6);  accx = fmaf(__int_as_float(p3.y), f.x, accx); accy = fmaf(__int_as_float(p3.y), f.y, accy);
        f = __half22float2(x7);  accx = fmaf(__int_as_float(p3.w), f.x, accx); accy = fmaf(__int_as_float(p3.w), f.y, accy);
        f = __half22float2(x8);  accx = fmaf(__int_as_float(p4.y), f.x, accx); accy = fmaf(__int_as_float(p4.y), f.y, accy);
        f = __half22float2(x9);  accx = fmaf(__int_as_float(p4.w), f.x, accx); accy = fmaf(__int_as_float(p4.w), f.y, accy);
        f = __half22float2(x10); accx = fmaf(__int_as_float(p5.y), f.x, accx); accy = fmaf(__int_as_float(p5.y), f.y, accy);
        f = __half22float2(x11); accx = fmaf(__int_as_float(p5.w), f.x, accx); accy = fmaf(__int_as_float(p5.w), f.y, accy);
        f = __half22float2(x12); accx = fmaf(__int_as_float(p6.y), f.x, accx); accy = fmaf(__int_as_float(p6.y), f.y, accy);
        f = __half22float2(x13); accx = fmaf(__int_as_float(p6.w), f.x, accx); accy = fmaf(__int_as_float(p6.w), f.y, accy);
        f = __half22float2(x14); accx = fmaf(__int_as_float(p7.y), f.x, accx); accy = fmaf(__int_as_float(p7.y), f.y, accy);
        f = __half22float2(x15); accx = fmaf(__int_as_float(p7.w), f.x, accx); accy = fmaf(__int_as_float(p7.w), f.y, accy);
        p0 = q0; p1 = q1; p2 = q2; p3 = q3;
        p4 = q4; p5 = q5; p6 = q6; p7 = q7;
    }
    if (s + 16 <= end) {
        float2 f;
        f = __half22float2(hc[(size_t)p0.x << 6]); accx = fmaf(__int_as_float(p0.y), f.x, accx); accy = fmaf(__int_as_float(p0.y), f.y, accy);
        f = __half22float2(hc[(size_t)p0.z << 6]); accx = fmaf(__int_as_float(p0.w), f.x, accx); accy = fmaf(__int_as_float(p0.w), f.y, accy);
        f = __half22float2(hc[(size_t)p1.x << 6]); accx = fmaf(__int_as_float(p1.y), f.x, accx); accy = fmaf(__int_as_float(p1.y), f.y, accy);
        f = __half22float2(hc[(size_t)p1.z << 6]); accx = fmaf(__int_as_float(p1.w), f.x, accx); accy = fmaf(__int_as_float(p1.w), f.y, accy);
        f = __half22float2(hc[(size_t)p2.x << 6]); accx = fmaf(__int_as_float(p2.y), f.x, accx); accy = fmaf(__int_as_float(p2.y), f.y, accy);
        f = __half22float2(hc[(size_t)p2.z << 6]); accx = fmaf(__int_as_float(p2.w), f.x, accx); accy = fmaf(__int_as_float(p2.w), f.y, accy);
        f = __half22float2(hc[(size_t)p3.x << 6]); accx = fmaf(__int_as_float(p3.y), f.x, accx); accy = fmaf(__int_as_float(p3.y), f.y, accy);
        f = __half22float2(hc[(size_t)p3.z << 6]); accx = fmaf(__int_as_float(p3.w), f.x, accx); accy = fmaf(__int_as_float(p3.w), f.y, accy);
        f = __half22float2(hc[(size_t)p4.x << 6]); accx = fmaf(__int_as_float(p4.y), f.x, accx); accy = fmaf(__int_as_float(p4.y), f.y, accy);
        f = __half22float2(hc[(size_t)p4.z << 6]); accx = fmaf(__int_as_float(p4.w), f.x, accx); accy = fmaf(__int_as_float(p4.w), f.y, accy);
        f = __half22float2(hc[(size_t)p5.x << 6]); accx = fmaf(__int_as_float(p5.y), f.x, accx); accy = fmaf(__int_as_float(p5.y), f.y, accy);
        f = __half22float2(hc[(size_t)p5.z << 6]); accx = fmaf(__int_as_float(p5.w), f.x, accx); accy = fmaf(__int_as_float(p5.w), f.y, accy);
        f = __half22float2(hc[(size_t)p6.x << 6]); accx = fmaf(__int_as_float(p6.y), f.x, accx); accy = fmaf(__int_as_float(p6.y), f.y, accy);
        f = __half22float2(hc[(size_t)p6.z << 6]); accx = fmaf(__int_as_float(p6.w), f.x, accx); accy = fmaf(__int_as_float(p6.w), f.y, accy);
        f = __half22float2(hc[(size_t)p7.x << 6]); accx = fmaf(__int_as_float(p7.y), f.x, accx); accy = fmaf(__int_as_float(p7.y), f.y, accy);
        f = __half22float2(hc[(size_t)p7.z << 6]); accx = fmaf(__int_as_float(p7.w), f.x, accx); accy = fmaf(__int_as_float(p7.w), f.y, accy);
        s += 16;
    }
    if (s + 8 <= end) {
        int4 a0 = *(const int4*)(sorted + s);
        int4 a1 = *(const int4*)(sorted + s + 2);
        int4 a2 = *(const int4*)(sorted + s + 4);
        int4 a3 = *(const int4*)(sorted + s + 6);
        float2 f;
        f = __half22float2(hc[(size_t)a0.x << 6]); accx = fmaf(__int_as_float(a0.y), f.x, accx); accy = fmaf(__int_as_float(a0.y), f.y, accy);
        f = __half22float2(hc[(size_t)a0.z << 6]); accx = fmaf(__int_as_float(a0.w), f.x, accx); accy = fmaf(__int_as_float(a0.w), f.y, accy);
        f = __half22float2(hc[(size_t)a1.x << 6]); accx = fmaf(__int_as_float(a1.y), f.x, accx); accy = fmaf(__int_as_float(a1.y), f.y, accy);
        f = __half22float2(hc[(size_t)a1.z << 6]); accx = fmaf(__int_as_float(a1.w), f.x, accx); accy = fmaf(__int_as_float(a1.w), f.y, accy);
        f = __half22float2(hc[(size_t)a2.x << 6]); accx = fmaf(__int_as_float(a2.y), f.x, accx); accy = fmaf(__int_as_float(a2.y), f.y, accy);
        f = __half22float2(hc[(size_t)a2.z << 6]); accx = fmaf(__int_as_float(a2.w), f.x, accx); accy = fmaf(__int_as_float(a2.w), f.y, accy);
        f = __half22float2(hc[(size_t)a3.x << 6]); accx = fmaf(__int_as_float(a3.y), f.x, accx); accy = fmaf(__int_as_float(a3.y), f.y, accy);
        f = __half22float2(hc[(size_t)a3.z << 6]); accx = fmaf(__int_as_float(a3.w), f.x, accx); accy = fmaf(__int_as_float(a3.w), f.y, accy);
        s += 8;
    }
    for (; s + 2 <= end; s += 2) {
        int4 p = *(const int4*)(sorted + s);
        float2 f;
        f = __half22float2(hc[(size_t)p.x << 6]); accx = fmaf(__int_as_float(p.y), f.x, accx); accy = fmaf(__int_as_float(p.y), f.y, accy);
        f = __half22float2(hc[(size_t)p.z << 6]); accx = fmaf(__int_as_float(p.w), f.x, accx); accy = fmaf(__int_as_float(p.w), f.y, accy);
    }
    if (s < end) {
        int2 rr = sorted[s];
        float w = __int_as_float(rr.y);
        float2 f = __half22float2(hc[(size_t)rr.x << 6]);
        accx = fmaf(w, f.x, accx); accy = fmaf(w, f.y, accy);
    }
    float2 o;
    if (EPI) {
        float nd = norm_dst[node];
        o.x = fmaxf(fmaf(accx, nd, bias[lane * 2]), 0.f);
        o.y = fmaxf(fmaf(accy, nd, bias[lane * 2 + 1]), 0.f);
    } else {
        o.x = accx; o.y = accy;
    }
    *(float2*)(out + ((size_t)node << 7) + lane * 2) = o;
}

// ---------------- FUSED double-GEMM: h1 = relu((A@W0)*nd + b0); t = h1@W1 -> fp16 ----------------
__global__ __launch_bounds__(256) void gemmfused_kernel(const float* __restrict__ A,
                                                        const float* __restrict__ W0, const float* __restrict__ b0,
                                                        const float* __restrict__ W1,
                                                        const float* __restrict__ norm_dst,
                                                        __half* __restrict__ out_h, int n) {
    __shared__ __align__(16) float sAT[D][GM + 2];
    int tid = threadIdx.x;
    int row0 = blockIdx.x * GM;
    for (int i = tid; i < GM * 32; i += 256) {
        int r = i >> 5;
        int kq = i & 31;
        int rr = row0 + r;
        float4 v = make_float4(0.f, 0.f, 0.f, 0.f);
        if (rr < n) v = *(const float4*)(A + (size_t)rr * D + kq * 4);
        sAT[kq * 4 + 0][r] = v.x;
        sAT[kq * 4 + 1][r] = v.y;
        sAT[kq * 4 + 2][r] = v.z;
        sAT[kq * 4 + 3][r] = v.w;
    }
    __syncthreads();
    int tx = tid & 15;
    int ty = tid >> 4;
    int c0 = tx * 8;
    int r0 = ty * 2;
    float acc0[8], acc1[8];
#pragma unroll
    for (int j = 0; j < 8; ++j) { acc0[j] = 0.f; acc1[j] = 0.f; }
    {
        const float* Wk = W0 + c0;
#pragma unroll 4
        for (int k = 0; k < D; ++k) {
            float2 a = *(const float2*)&sAT[k][r0];
            float4 w0 = *(const float4*)(Wk);
            float4 w1 = *(const float4*)(Wk + 4);
            Wk += D;
            acc0[0] = fmaf(a.x, w0.x, acc0[0]);
            acc0[1] = fmaf(a.x, w0.y, acc0[1]);
            acc0[2] = fmaf(a.x, w0.z, acc0[2]);
            acc0[3] = fmaf(a.x, w0.w, acc0[3]);
            acc0[4] = fmaf(a.x, w1.x, acc0[4]);
            acc0[5] = fmaf(a.x, w1.y, acc0[5]);
            acc0[6] = fmaf(a.x, w1.z, acc0[6]);
            acc0[7] = fmaf(a.x, w1.w, acc0[7]);
            acc1[0] = fmaf(a.y, w0.x, acc1[0]);
            acc1[1] = fmaf(a.y, w0.y, acc1[1]);
            acc1[2] = fmaf(a.y, w0.z, acc1[2]);
            acc1[3] = fmaf(a.y, w0.w, acc1[3]);
            acc1[4] = fmaf(a.y, w1.x, acc1[4]);
            acc1[5] = fmaf(a.y, w1.y, acc1[5]);
            acc1[6] = fmaf(a.y, w1.z, acc1[6]);
            acc1[7] = fmaf(a.y, w1.w, acc1[7]);
        }
    }
    __syncthreads();
#pragma unroll 2
    for (int rr = 0; rr < 2; ++rr) {
        int r = row0 + r0 + rr;
        if (r >= n) continue;
        float* acc = rr ? acc1 : acc0;
        float nd = norm_dst[r];
#pragma unroll
        for (int j = 0; j < 8; ++j)
            sAT[c0 + j][r0 + rr] = fmaxf(fmaf(acc[j], nd, b0[c0 + j]), 0.f);
    }
    __syncthreads();
#pragma unroll
    for (int j = 0; j < 8; ++j) { acc0[j] = 0.f; acc1[j] = 0.f; }
    {
        const float* Wk = W1 + c0;
#pragma unroll 4
        for (int k = 0; k < D; ++k) {
            float2 a = *(const float2*)&sAT[k][r0];
            float4 w0 = *(const float4*)(Wk);
            float4 w1 = *(const float4*)(Wk + 4);
            Wk += D;
            acc0[0] = fmaf(a.x, w0.x, acc0[0]);
            acc0[1] = fmaf(a.x, w0.y, acc0[1]);
            acc0[2] = fmaf(a.x, w0.z, acc0[2]);
            acc0[3] = fmaf(a.x, w0.w, acc0[3]);
            acc0[4] = fmaf(a.x, w1.x, acc0[4]);
            acc0[5] = fmaf(a.x, w1.y, acc0[5]);
            acc0[6] = fmaf(a.x, w1.z, acc0[6]);
            acc0[7] = fmaf(a.x, w1.w, acc0[7]);
            acc1[0] = fmaf(a.y, w0.x, acc1[0]);
            acc1[1] = fmaf(a.y, w0.y, acc1[1]);
            acc1[2] = fmaf(a.y, w0.z, acc1[2]);
            acc1[3] = fmaf(a.y, w0.w, acc1[3]);
            acc1[4] = fmaf(a.y, w1.x, acc1[4]);
            acc1[5] = fmaf(a.y, w1.y, acc1[5]);
            acc1[6] = fmaf(a.y, w1.z, acc1[6]);
            acc1[7] = fmaf(a.y, w1.w, acc1[7]);
        }
    }
#pragma unroll 2
    for (int rr = 0; rr < 2; ++rr) {
        int r = row0 + r0 + rr;
        if (r >= n) continue;
        float* acc = rr ? acc1 : acc0;
        __half2 h0 = __floats2half2_rn(acc[0], acc[1]);
        __half2 h1 = __floats2half2_rn(acc[2], acc[3]);
        __half2 h2 = __floats2half2_rn(acc[4], acc[5]);
        __half2 h3 = __floats2half2_rn(acc[6], acc[7]);
        __half* p = out_h + (size_t)r * D + c0;
        *(__half2*)(p + 0) = h0;
        *(__half2*)(p + 2) = h1;
        *(__half2*)(p + 4) = h2;
        *(__half2*)(p + 6) = h3;
    }
}

extern "C" void kernel_launch(void* const* d_in, const int* in_sizes, int n_in,
                              void* d_out, int out_size, void* d_ws, size_t ws_size,
                              hipStream_t stream) {
    const float* x  = (const float*)d_in[0];
    const float* ew = (const float*)d_in[1];
    const float* W0 = (const float*)d_in[2];
    const float* b0 = (const float*)d_in[3];
    const float* W1 = (const float*)d_in[4];
    const float* b1 = (const float*)d_in[5];
    const int* src  = (const int*)d_in[6];
    const int* dst  = (const int*)d_in[7];
    float* out = (float*)d_out;

    int n = in_sizes[0] / D;   // 10000
    int E = in_sizes[6];       // 640000
    if (n <= 0 || E <= 0) return;

    char* ws = (char*)d_ws;
    size_t off = 0;
    auto alloc = [&](size_t bytes) -> void* {
        void* p = ws + off;
        off = (off + bytes + 255) & ~(size_t)255;
        return p;
    };
    int* row_start  = (int*)alloc(((size_t)n + 1) * 4);
    float* norm_src = (float*)alloc((size_t)n * 4);
    float* norm_dst = (float*)alloc((size_t)n * 4);
    int* qtot_d     = (int*)alloc((size_t)Q * n * 4);   // becomes qbase
    int* qtot_s     = (int*)alloc((size_t)Q * n * 4);
    int2* sorted    = (int2*)alloc((size_t)E * 8);
    int* pd         = (int*)alloc((size_t)NB * n * 4);
    unsigned short* ps = (unsigned short*)alloc((size_t)NB * n * 2);
    float* B1       = (float*)alloc((size_t)n * D * 4); // agg1 output (fp32)
    __half* xh      = (__half*)alloc((size_t)n * D * 2); // x as fp16
    __half* th      = (__half*)alloc((size_t)n * D * 2); // t = h1@W1 as fp16
    int* bar        = (int*)alloc(256);                  // grid-barrier counter
    int* part_g     = (int*)alloc(64 * 4);               // per-slice deg partials
    int* base_g     = (int*)alloc(64 * 4);               // scanned bases

    int nb4 = (n + 1023) / 1024;           // 1024-bin slices
    int ab = (n + 3) / 4;                  // one wave per node
    int gb = (n + GM - 1) / GM;

    hipMemsetAsync(bar, 0, 4, stream);
    preprocess_kernel<<<NB, 256, 0, stream>>>(src, dst, x, xh, n * D / 4, ew,
                                              pd, ps, qtot_d, qtot_s,
                                              row_start, norm_src, norm_dst, sorted,
                                              bar, part_g, base_g, E, n, nb4);

    // layer 1 agg -> B1; fused [gemm1 + relu + gemm2-matmul] -> th; layer 2 agg + final epilogue -> out
    agg_kernel<0><<<ab, 256, 0, stream>>>(xh, row_start, sorted, B1, nullptr, nullptr, n);
    gemmfused_kernel<<<gb, 256, 0, stream>>>(B1, W0, b0, W1, norm_dst, th, n);
    agg_kernel<1><<<ab, 256, 0, stream>>>(th, row_start, sorted, out, norm_dst, b1, n);
}

// Round 17
// 182.201 us; speedup vs baseline: 1.4181x; 1.4181x over previous
//
#include <hip/hip_runtime.h>
#include <hip/hip_fp16.h>

#define D 128
#define NB 256          // counting-sort chunks (one block each)
#define Q 8             // quarters for the b-dimension scan
#define BQ (NB / Q)     // blocks per quarter = 32
#define NBINS_MAX 10016 // max nodes supported by LDS histogram (~40 KB)
#define GM 32           // gemm rows per block

// ---------------- hist (+ folded x->fp16 cast as phase 0) ----------------
__global__ __launch_bounds__(256) void hist_kernel(const int* __restrict__ src, const int* __restrict__ dst,
                                                   const float* __restrict__ x, __half* __restrict__ xh, int total4,
                                                   int* __restrict__ pd, unsigned short* __restrict__ ps,
                                                   int E, int n) {
    __shared__ __align__(16) int hd[NBINS_MAX];
    __shared__ __align__(16) int hs[NBINS_MAX];
    int b = blockIdx.x, t = threadIdx.x;
    for (int i = b * 256 + t; i < total4; i += NB * 256) {
        float4 v = *(const float4*)(x + (size_t)i * 4);
        __half2 a = __floats2half2_rn(v.x, v.y);
        __half2 c = __floats2half2_rn(v.z, v.w);
        *(__half2*)(xh + (size_t)i * 4) = a;
        *(__half2*)(xh + (size_t)i * 4 + 2) = c;
    }
    int chunk = (E + NB - 1) / NB;
    int e0 = b * chunk, e1 = min(e0 + chunk, E);
    int nq = (n + 3) >> 2;
    for (int i = t; i < nq; i += 256) {
        *(int4*)(&hd[i * 4]) = make_int4(0, 0, 0, 0);
        *(int4*)(&hs[i * 4]) = make_int4(0, 0, 0, 0);
    }
    __syncthreads();
    for (int e = e0 + t; e < e1; e += 256) {
        atomicAdd(&hd[dst[e]], 1);
        atomicAdd(&hs[src[e]], 1);
    }
    __syncthreads();
    int nf = n >> 2;
    for (int i = t; i < nf; i += 256) {
        int4 h = *(const int4*)(&hd[i * 4]);
        *(int4*)(pd + (size_t)b * n + i * 4) = h;
        int4 s = *(const int4*)(&hs[i * 4]);
        uint2 u;
        u.x = (unsigned)(s.x & 0xFFFF) | ((unsigned)(s.y & 0xFFFF) << 16);
        u.y = (unsigned)(s.z & 0xFFFF) | ((unsigned)(s.w & 0xFFFF) << 16);
        *(uint2*)(ps + (size_t)b * n + i * 4) = u;
    }
    for (int i = nf * 4 + t; i < n; i += 256) {
        pd[(size_t)b * n + i] = hd[i];
        ps[(size_t)b * n + i] = (unsigned short)hs[i];
    }
}

// ---------------- within-quarter exclusive scan of pd along b (in place, 4 bins/thread) ----------------
__global__ __launch_bounds__(256) void colscan_kernel(int* __restrict__ pd, const unsigned short* __restrict__ ps,
                                                      int* __restrict__ qtot_d, int* __restrict__ qtot_s, int n) {
    int bin4 = (blockIdx.x * 256 + threadIdx.x) * 4;
    int q = blockIdx.y;
    if (bin4 >= n) return;
    int b0 = q * BQ;
    if (bin4 + 3 < n) {
        int4 run = make_int4(0, 0, 0, 0);
        int4 ssum = make_int4(0, 0, 0, 0);
#pragma unroll 8
        for (int j = 0; j < BQ; ++j) {
            size_t idx = (size_t)(b0 + j) * n + bin4;
            int4 v = *(const int4*)(pd + idx);
            *(int4*)(pd + idx) = run;
            run.x += v.x; run.y += v.y; run.z += v.z; run.w += v.w;
            uint2 u = *(const uint2*)(ps + idx);
            ssum.x += (int)(u.x & 0xFFFF); ssum.y += (int)(u.x >> 16);
            ssum.z += (int)(u.y & 0xFFFF); ssum.w += (int)(u.y >> 16);
        }
        *(int4*)(qtot_d + (size_t)q * n + bin4) = run;
        *(int4*)(qtot_s + (size_t)q * n + bin4) = ssum;
    } else {
        for (int bin = bin4; bin < n; ++bin) {
            int run = 0, ssum = 0;
            for (int j = 0; j < BQ; ++j) {
                size_t idx = (size_t)(b0 + j) * n + bin;
                int v = pd[idx];
                pd[idx] = run;
                run += v;
                ssum += (int)ps[idx];
            }
            qtot_d[(size_t)q * n + bin] = run;
            qtot_s[(size_t)q * n + bin] = ssum;
        }
    }
}

// ---------------- fused finalize + scan: single block, LDS-staged ----------------
__global__ __launch_bounds__(1024) void finscan_kernel(int* __restrict__ qtot_d, const int* __restrict__ qtot_s,
                                                       int* __restrict__ row_start,
                                                       float* __restrict__ norm_src, float* __restrict__ norm_dst,
                                                       int n) {
    __shared__ int deg[NBINS_MAX];
    __shared__ int part[1024];
    int t = threadIdx.x;
    for (int b4 = t * 4; b4 < n; b4 += 4096) {
        if (b4 + 3 < n) {
            int4 qv[Q];
#pragma unroll
            for (int q = 0; q < Q; ++q) qv[q] = *(const int4*)(qtot_d + (size_t)q * n + b4);
            int4 run = make_int4(0, 0, 0, 0);
#pragma unroll
            for (int q = 0; q < Q; ++q) {
                *(int4*)(qtot_d + (size_t)q * n + b4) = run;
                run.x += qv[q].x; run.y += qv[q].y; run.z += qv[q].z; run.w += qv[q].w;
            }
            *(int4*)(&deg[b4]) = run;
            norm_dst[b4 + 0] = rsqrtf(fmaxf((float)run.x, 1.0f));
            norm_dst[b4 + 1] = rsqrtf(fmaxf((float)run.y, 1.0f));
            norm_dst[b4 + 2] = rsqrtf(fmaxf((float)run.z, 1.0f));
            norm_dst[b4 + 3] = rsqrtf(fmaxf((float)run.w, 1.0f));
            int4 st = make_int4(0, 0, 0, 0);
#pragma unroll
            for (int q = 0; q < Q; ++q) {
                int4 v = *(const int4*)(qtot_s + (size_t)q * n + b4);
                st.x += v.x; st.y += v.y; st.z += v.z; st.w += v.w;
            }
            norm_src[b4 + 0] = rsqrtf(fmaxf((float)st.x, 1.0f));
            norm_src[b4 + 1] = rsqrtf(fmaxf((float)st.y, 1.0f));
            norm_src[b4 + 2] = rsqrtf(fmaxf((float)st.z, 1.0f));
            norm_src[b4 + 3] = rsqrtf(fmaxf((float)st.w, 1.0f));
        } else {
            for (int bin = b4; bin < n; ++bin) {
                int run = 0;
                for (int q = 0; q < Q; ++q) {
                    size_t i = (size_t)q * n + bin;
                    int v = qtot_d[i];
                    qtot_d[i] = run;
                    run += v;
                }
                deg[bin] = run;
                norm_dst[bin] = rsqrtf(fmaxf((float)run, 1.0f));
                int tot = 0;
                for (int q = 0; q < Q; ++q) tot += qtot_s[(size_t)q * n + bin];
                norm_src[bin] = rsqrtf(fmaxf((float)tot, 1.0f));
            }
        }
    }
    __syncthreads();
    int ipt = (n + 1023) / 1024;
    int lo = min(t * ipt, n), hi = min(lo + ipt, n);
    int s = 0;
    for (int i = lo; i < hi; ++i) s += deg[i];
    part[t] = s;
    __syncthreads();
    for (int off = 1; off < 1024; off <<= 1) {
        int v = 0;
        if (t >= off) v = part[t - off];
        __syncthreads();
        if (t >= off) part[t] += v;
        __syncthreads();
    }
    int run = part[t] - s;
    for (int i = lo; i < hi; ++i) {
        int v = deg[i];
        row_start[i] = run;
        run += v;
    }
    if (t == 1023) row_start[n] = part[1023];
}

// ---------------- CSR fill: LDS cursor = row_start + qbase + pd (int4 seed) ----------------
// Record weight = ew[e] * norm_src[src[e]]  (layer-invariant; folds the src-norm).
__global__ __launch_bounds__(256) void fill_kernel(const int* __restrict__ src, const int* __restrict__ dst,
                                                   const float* __restrict__ ew, const float* __restrict__ ns,
                                                   const int* __restrict__ row_start, const int* __restrict__ qbase,
                                                   const int* __restrict__ pd,
                                                   int2* __restrict__ sorted, int E, int n) {
    __shared__ __align__(16) int cursor[NBINS_MAX];
    int b = blockIdx.x, t = threadIdx.x;
    int q = b / BQ;
    int chunk = (E + NB - 1) / NB;
    int e0 = b * chunk, e1 = min(e0 + chunk, E);
    int nf = n >> 2;
    for (int i = t; i < nf; i += 256) {
        int4 r = *(const int4*)(row_start + i * 4);
        int4 a = *(const int4*)(qbase + (size_t)q * n + i * 4);
        int4 c = *(const int4*)(pd + (size_t)b * n + i * 4);
        *(int4*)(&cursor[i * 4]) = make_int4(r.x + a.x + c.x, r.y + a.y + c.y,
                                             r.z + a.z + c.z, r.w + a.w + c.w);
    }
    for (int i = nf * 4 + t; i < n; i += 256)
        cursor[i] = row_start[i] + qbase[(size_t)q * n + i] + pd[(size_t)b * n + i];
    __syncthreads();
    for (int e = e0 + t; e < e1; e += 256) {
        int d = dst[e];
        int slot = atomicAdd(&cursor[d], 1);
        int s = src[e];
        int2 rec;
        rec.x = s;
        rec.y = __float_as_int(ew[e] * ns[s]);
        sorted[slot] = rec;
    }
}

// ---------------- full-row aggregation: one wave per node, half2 per lane ----------------
// EPI=0: raw fp32 store (feeds gemmfused). EPI=1: final epilogue at store:
// out = relu(acc * norm_dst[node] + bias[feature])  -- layer-2 reorder folds
// the whole second gemm-epilogue here.
template <int EPI>
__global__ __launch_bounds__(256) void agg_kernel(const __half* __restrict__ h, const int* __restrict__ row_start,
                                                  const int2* __restrict__ sorted, float* __restrict__ out,
                                                  const float* __restrict__ norm_dst, const float* __restrict__ bias,
                                                  int n) {
    int wave = threadIdx.x >> 6;
    int lane = threadIdx.x & 63;
    int node = blockIdx.x * 4 + wave;
    if (node >= n) return;
    const __half2* hc = (const __half2*)h + lane;   // row r at hc[r<<6]
    int beg = __builtin_amdgcn_readfirstlane(row_start[node]);
    int end = __builtin_amdgcn_readfirstlane(row_start[node + 1]);
    float accx = 0.f, accy = 0.f;
    int s = beg;
    if (s < end && (s & 1)) {
        int2 rr = sorted[s];
        float w = __int_as_float(rr.y);
        float2 f = __half22float2(hc[(size_t)rr.x << 6]);
        accx = fmaf(w, f.x, accx); accy = fmaf(w, f.y, accy);
        ++s;
    }
    int4 p0, p1, p2, p3, p4, p5, p6, p7;
    if (s + 16 <= end) {
        p0 = *(const int4*)(sorted + s);
        p1 = *(const int4*)(sorted + s + 2);
        p2 = *(const int4*)(sorted + s + 4);
        p3 = *(const int4*)(sorted + s + 6);
        p4 = *(const int4*)(sorted + s + 8);
        p5 = *(const int4*)(sorted + s + 10);
        p6 = *(const int4*)(sorted + s + 12);
        p7 = *(const int4*)(sorted + s + 14);
    }
    for (; s + 32 <= end; s += 16) {
        int4 q0 = *(const int4*)(sorted + s + 16);
        int4 q1 = *(const int4*)(sorted + s + 18);
        int4 q2 = *(const int4*)(sorted + s + 20);
        int4 q3 = *(const int4*)(sorted + s + 22);
        int4 q4 = *(const int4*)(sorted + s + 24);
        int4 q5 = *(const int4*)(sorted + s + 26);
        int4 q6 = *(const int4*)(sorted + s + 28);
        int4 q7 = *(const int4*)(sorted + s + 30);
        __half2 x0  = hc[(size_t)p0.x << 6];
        __half2 x1  = hc[(size_t)p0.z << 6];
        __half2 x2  = hc[(size_t)p1.x << 6];
        __half2 x3  = hc[(size_t)p1.z << 6];
        __half2 x4  = hc[(size_t)p2.x << 6];
        __half2 x5  = hc[(size_t)p2.z << 6];
        __half2 x6  = hc[(size_t)p3.x << 6];
        __half2 x7  = hc[(size_t)p3.z << 6];
        __half2 x8  = hc[(size_t)p4.x << 6];
        __half2 x9  = hc[(size_t)p4.z << 6];
        __half2 x10 = hc[(size_t)p5.x << 6];
        __half2 x11 = hc[(size_t)p5.z << 6];
        __half2 x12 = hc[(size_t)p6.x << 6];
        __half2 x13 = hc[(size_t)p6.z << 6];
        __half2 x14 = hc[(size_t)p7.x << 6];
        __half2 x15 = hc[(size_t)p7.z << 6];
        float2 f;
        f = __half22float2(x0);  accx = fmaf(__int_as_float(p0.y), f.x, accx); accy = fmaf(__int_as_float(p0.y), f.y, accy);
        f = __half22float2(x1);  accx = fmaf(__int_as_float(p0.w), f.x, accx); accy = fmaf(__int_as_float(p0.w), f.y, accy);
        f = __half22float2(x2);  accx = fmaf(__int_as_float(p1.y), f.x, accx); accy = fmaf(__int_as_float(p1.y), f.y, accy);
        f = __half22float2(x3);  accx = fmaf(__int_as_float(p1.w), f.x, accx); accy = fmaf(__int_as_float(p1.w), f.y, accy);
        f = __half22float2(x4);  accx = fmaf(__int_as_float(p2.y), f.x, accx); accy = fmaf(__int_as_float(p2.y), f.y, accy);
        f = __half22float2(x5);  accx = fmaf(__int_as_float(p2.w), f.x, accx); accy = fmaf(__int_as_float(p2.w), f.y, accy);
        f = __half22float2(x6);  accx = fmaf(__int_as_float(p3.y), f.x, accx); accy = fmaf(__int_as_float(p3.y), f.y, accy);
        f = __half22float2(x7);  accx = fmaf(__int_as_float(p3.w), f.x, accx); accy = fmaf(__int_as_float(p3.w), f.y, accy);
        f = __half22float2(x8);  accx = fmaf(__int_as_float(p4.y), f.x, accx); accy = fmaf(__int_as_float(p4.y), f.y, accy);
        f = __half22float2(x9);  accx = fmaf(__int_as_float(p4.w), f.x, accx); accy = fmaf(__int_as_float(p4.w), f.y, accy);
        f = __half22float2(x10); accx = fmaf(__int_as_float(p5.y), f.x, accx); accy = fmaf(__int_as_float(p5.y), f.y, accy);
        f = __half22float2(x11); accx = fmaf(__int_as_float(p5.w), f.x, accx); accy = fmaf(__int_as_float(p5.w), f.y, accy);
        f = __half22float2(x12); accx = fmaf(__int_as_float(p6.y), f.x, accx); accy = fmaf(__int_as_float(p6.y), f.y, accy);
        f = __half22float2(x13); accx = fmaf(__int_as_float(p6.w), f.x, accx); accy = fmaf(__int_as_float(p6.w), f.y, accy);
        f = __half22float2(x14); accx = fmaf(__int_as_float(p7.y), f.x, accx); accy = fmaf(__int_as_float(p7.y), f.y, accy);
        f = __half22float2(x15); accx = fmaf(__int_as_float(p7.w), f.x, accx); accy = fmaf(__int_as_float(p7.w), f.y, accy);
        p0 = q0; p1 = q1; p2 = q2; p3 = q3;
        p4 = q4; p5 = q5; p6 = q6; p7 = q7;
    }
    if (s + 16 <= end) {
        float2 f;
        f = __half22float2(hc[(size_t)p0.x << 6]); accx = fmaf(__int_as_float(p0.y), f.x, accx); accy = fmaf(__int_as_float(p0.y), f.y, accy);
        f = __half22float2(hc[(size_t)p0.z << 6]); accx = fmaf(__int_as_float(p0.w), f.x, accx); accy = fmaf(__int_as_float(p0.w), f.y, accy);
        f = __half22float2(hc[(size_t)p1.x << 6]); accx = fmaf(__int_as_float(p1.y), f.x, accx); accy = fmaf(__int_as_float(p1.y), f.y, accy);
        f = __half22float2(hc[(size_t)p1.z << 6]); accx = fmaf(__int_as_float(p1.w), f.x, accx); accy = fmaf(__int_as_float(p1.w), f.y, accy);
        f = __half22float2(hc[(size_t)p2.x << 6]); accx = fmaf(__int_as_float(p2.y), f.x, accx); accy = fmaf(__int_as_float(p2.y), f.y, accy);
        f = __half22float2(hc[(size_t)p2.z << 6]); accx = fmaf(__int_as_float(p2.w), f.x, accx); accy = fmaf(__int_as_float(p2.w), f.y, accy);
        f = __half22float2(hc[(size_t)p3.x << 6]); accx = fmaf(__int_as_float(p3.y), f.x, accx); accy = fmaf(__int_as_float(p3.y), f.y, accy);
        f = __half22float2(hc[(size_t)p3.z << 6]); accx = fmaf(__int_as_float(p3.w), f.x, accx); accy = fmaf(__int_as_float(p3.w), f.y, accy);
        f = __half22float2(hc[(size_t)p4.x << 6]); accx = fmaf(__int_as_float(p4.y), f.x, accx); accy = fmaf(__int_as_float(p4.y), f.y, accy);
        f = __half22float2(hc[(size_t)p4.z << 6]); accx = fmaf(__int_as_float(p4.w), f.x, accx); accy = fmaf(__int_as_float(p4.w), f.y, accy);
        f = __half22float2(hc[(size_t)p5.x << 6]); accx = fmaf(__int_as_float(p5.y), f.x, accx); accy = fmaf(__int_as_float(p5.y), f.y, accy);
        f = __half22float2(hc[(size_t)p5.z << 6]); accx = fmaf(__int_as_float(p5.w), f.x, accx); accy = fmaf(__int_as_float(p5.w), f.y, accy);
        f = __half22float2(hc[(size_t)p6.x << 6]); accx = fmaf(__int_as_float(p6.y), f.x, accx); accy = fmaf(__int_as_float(p6.y), f.y, accy);
        f = __half22float2(hc[(size_t)p6.z << 6]); accx = fmaf(__int_as_float(p6.w), f.x, accx); accy = fmaf(__int_as_float(p6.w), f.y, accy);
        f = __half22float2(hc[(size_t)p7.x << 6]); accx = fmaf(__int_as_float(p7.y), f.x, accx); accy = fmaf(__int_as_float(p7.y), f.y, accy);
        f = __half22float2(hc[(size_t)p7.z << 6]); accx = fmaf(__int_as_float(p7.w), f.x, accx); accy = fmaf(__int_as_float(p7.w), f.y, accy);
        s += 16;
    }
    if (s + 8 <= end) {
        int4 a0 = *(const int4*)(sorted + s);
        int4 a1 = *(const int4*)(sorted + s + 2);
        int4 a2 = *(const int4*)(sorted + s + 4);
        int4 a3 = *(const int4*)(sorted + s + 6);
        float2 f;
        f = __half22float2(hc[(size_t)a0.x << 6]); accx = fmaf(__int_as_float(a0.y), f.x, accx); accy = fmaf(__int_as_float(a0.y), f.y, accy);
        f = __half22float2(hc[(size_t)a0.z << 6]); accx = fmaf(__int_as_float(a0.w), f.x, accx); accy = fmaf(__int_as_float(a0.w), f.y, accy);
        f = __half22float2(hc[(size_t)a1.x << 6]); accx = fmaf(__int_as_float(a1.y), f.x, accx); accy = fmaf(__int_as_float(a1.y), f.y, accy);
        f = __half22float2(hc[(size_t)a1.z << 6]); accx = fmaf(__int_as_float(a1.w), f.x, accx); accy = fmaf(__int_as_float(a1.w), f.y, accy);
        f = __half22float2(hc[(size_t)a2.x << 6]); accx = fmaf(__int_as_float(a2.y), f.x, accx); accy = fmaf(__int_as_float(a2.y), f.y, accy);
        f = __half22float2(hc[(size_t)a2.z << 6]); accx = fmaf(__int_as_float(a2.w), f.x, accx); accy = fmaf(__int_as_float(a2.w), f.y, accy);
        f = __half22float2(hc[(size_t)a3.x << 6]); accx = fmaf(__int_as_float(a3.y), f.x, accx); accy = fmaf(__int_as_float(a3.y), f.y, accy);
        f = __half22float2(hc[(size_t)a3.z << 6]); accx = fmaf(__int_as_float(a3.w), f.x, accx); accy = fmaf(__int_as_float(a3.w), f.y, accy);
        s += 8;
    }
    for (; s + 2 <= end; s += 2) {
        int4 p = *(const int4*)(sorted + s);
        float2 f;
        f = __half22float2(hc[(size_t)p.x << 6]); accx = fmaf(__int_as_float(p.y), f.x, accx); accy = fmaf(__int_as_float(p.y), f.y, accy);
        f = __half22float2(hc[(size_t)p.z << 6]); accx = fmaf(__int_as_float(p.w), f.x, accx); accy = fmaf(__int_as_float(p.w), f.y, accy);
    }
    if (s < end) {
        int2 rr = sorted[s];
        float w = __int_as_float(rr.y);
        float2 f = __half22float2(hc[(size_t)rr.x << 6]);
        accx = fmaf(w, f.x, accx); accy = fmaf(w, f.y, accy);
    }
    float2 o;
    if (EPI) {
        float nd = norm_dst[node];
        o.x = fmaxf(fmaf(accx, nd, bias[lane * 2]), 0.f);
        o.y = fmaxf(fmaf(accy, nd, bias[lane * 2 + 1]), 0.f);
    } else {
        o.x = accx; o.y = accy;
    }
    *(float2*)(out + ((size_t)node << 7) + lane * 2) = o;
}

// ---------------- FUSED double-GEMM: h1 = relu((A@W0)*nd + b0); t = h1@W1 -> fp16 ----------------
// Layer-2 reorder: agg(h1*ns)@W1 == agg_records(h1@W1) since records fold ew*ns.
__global__ __launch_bounds__(256) void gemmfused_kernel(const float* __restrict__ A,
                                                        const float* __restrict__ W0, const float* __restrict__ b0,
                                                        const float* __restrict__ W1,
                                                        const float* __restrict__ norm_dst,
                                                        __half* __restrict__ out_h, int n) {
    __shared__ __align__(16) float sAT[D][GM + 2];
    int tid = threadIdx.x;
    int row0 = blockIdx.x * GM;
    for (int i = tid; i < GM * 32; i += 256) {
        int r = i >> 5;
        int kq = i & 31;
        int rr = row0 + r;
        float4 v = make_float4(0.f, 0.f, 0.f, 0.f);
        if (rr < n) v = *(const float4*)(A + (size_t)rr * D + kq * 4);
        sAT[kq * 4 + 0][r] = v.x;
        sAT[kq * 4 + 1][r] = v.y;
        sAT[kq * 4 + 2][r] = v.z;
        sAT[kq * 4 + 3][r] = v.w;
    }
    __syncthreads();
    int tx = tid & 15;
    int ty = tid >> 4;
    int c0 = tx * 8;
    int r0 = ty * 2;
    float acc0[8], acc1[8];
#pragma unroll
    for (int j = 0; j < 8; ++j) { acc0[j] = 0.f; acc1[j] = 0.f; }
    {
        const float* Wk = W0 + c0;
#pragma unroll 4
        for (int k = 0; k < D; ++k) {
            float2 a = *(const float2*)&sAT[k][r0];
            float4 w0 = *(const float4*)(Wk);
            float4 w1 = *(const float4*)(Wk + 4);
            Wk += D;
            acc0[0] = fmaf(a.x, w0.x, acc0[0]);
            acc0[1] = fmaf(a.x, w0.y, acc0[1]);
            acc0[2] = fmaf(a.x, w0.z, acc0[2]);
            acc0[3] = fmaf(a.x, w0.w, acc0[3]);
            acc0[4] = fmaf(a.x, w1.x, acc0[4]);
            acc0[5] = fmaf(a.x, w1.y, acc0[5]);
            acc0[6] = fmaf(a.x, w1.z, acc0[6]);
            acc0[7] = fmaf(a.x, w1.w, acc0[7]);
            acc1[0] = fmaf(a.y, w0.x, acc1[0]);
            acc1[1] = fmaf(a.y, w0.y, acc1[1]);
            acc1[2] = fmaf(a.y, w0.z, acc1[2]);
            acc1[3] = fmaf(a.y, w0.w, acc1[3]);
            acc1[4] = fmaf(a.y, w1.x, acc1[4]);
            acc1[5] = fmaf(a.y, w1.y, acc1[5]);
            acc1[6] = fmaf(a.y, w1.z, acc1[6]);
            acc1[7] = fmaf(a.y, w1.w, acc1[7]);
        }
    }
    __syncthreads();   // all phase-1 reads of sAT complete before overwrite
#pragma unroll 2
    for (int rr = 0; rr < 2; ++rr) {
        int r = row0 + r0 + rr;
        if (r >= n) continue;
        float* acc = rr ? acc1 : acc0;
        float nd = norm_dst[r];
#pragma unroll
        for (int j = 0; j < 8; ++j)
            sAT[c0 + j][r0 + rr] = fmaxf(fmaf(acc[j], nd, b0[c0 + j]), 0.f);  // h1 (no ns: folded in records)
    }
    __syncthreads();
#pragma unroll
    for (int j = 0; j < 8; ++j) { acc0[j] = 0.f; acc1[j] = 0.f; }
    {
        const float* Wk = W1 + c0;
#pragma unroll 4
        for (int k = 0; k < D; ++k) {
            float2 a = *(const float2*)&sAT[k][r0];
            float4 w0 = *(const float4*)(Wk);
            float4 w1 = *(const float4*)(Wk + 4);
            Wk += D;
            acc0[0] = fmaf(a.x, w0.x, acc0[0]);
            acc0[1] = fmaf(a.x, w0.y, acc0[1]);
            acc0[2] = fmaf(a.x, w0.z, acc0[2]);
            acc0[3] = fmaf(a.x, w0.w, acc0[3]);
            acc0[4] = fmaf(a.x, w1.x, acc0[4]);
            acc0[5] = fmaf(a.x, w1.y, acc0[5]);
            acc0[6] = fmaf(a.x, w1.z, acc0[6]);
            acc0[7] = fmaf(a.x, w1.w, acc0[7]);
            acc1[0] = fmaf(a.y, w0.x, acc1[0]);
            acc1[1] = fmaf(a.y, w0.y, acc1[1]);
            acc1[2] = fmaf(a.y, w0.z, acc1[2]);
            acc1[3] = fmaf(a.y, w0.w, acc1[3]);
            acc1[4] = fmaf(a.y, w1.x, acc1[4]);
            acc1[5] = fmaf(a.y, w1.y, acc1[5]);
            acc1[6] = fmaf(a.y, w1.z, acc1[6]);
            acc1[7] = fmaf(a.y, w1.w, acc1[7]);
        }
    }
#pragma unroll 2
    for (int rr = 0; rr < 2; ++rr) {
        int r = row0 + r0 + rr;
        if (r >= n) continue;
        float* acc = rr ? acc1 : acc0;
        __half2 h0 = __floats2half2_rn(acc[0], acc[1]);
        __half2 h1 = __floats2half2_rn(acc[2], acc[3]);
        __half2 h2 = __floats2half2_rn(acc[4], acc[5]);
        __half2 h3 = __floats2half2_rn(acc[6], acc[7]);
        __half* p = out_h + (size_t)r * D + c0;
        *(__half2*)(p + 0) = h0;
        *(__half2*)(p + 2) = h1;
        *(__half2*)(p + 4) = h2;
        *(__half2*)(p + 6) = h3;
    }
}

extern "C" void kernel_launch(void* const* d_in, const int* in_sizes, int n_in,
                              void* d_out, int out_size, void* d_ws, size_t ws_size,
                              hipStream_t stream) {
    const float* x  = (const float*)d_in[0];
    const float* ew = (const float*)d_in[1];
    const float* W0 = (const float*)d_in[2];
    const float* b0 = (const float*)d_in[3];
    const float* W1 = (const float*)d_in[4];
    const float* b1 = (const float*)d_in[5];
    const int* src  = (const int*)d_in[6];
    const int* dst  = (const int*)d_in[7];
    float* out = (float*)d_out;

    int n = in_sizes[0] / D;   // 10000
    int E = in_sizes[6];       // 640000
    if (n <= 0 || E <= 0) return;

    char* ws = (char*)d_ws;
    size_t off = 0;
    auto alloc = [&](size_t bytes) -> void* {
        void* p = ws + off;
        off = (off + bytes + 255) & ~(size_t)255;
        return p;
    };
    int* row_start  = (int*)alloc(((size_t)n + 1) * 4);
    float* norm_src = (float*)alloc((size_t)n * 4);
    float* norm_dst = (float*)alloc((size_t)n * 4);
    int* qtot_d     = (int*)alloc((size_t)Q * n * 4);   // becomes qbase in finscan
    int* qtot_s     = (int*)alloc((size_t)Q * n * 4);
    int2* sorted    = (int2*)alloc((size_t)E * 8);
    int* pd         = (int*)alloc((size_t)NB * n * 4);
    unsigned short* ps = (unsigned short*)alloc((size_t)NB * n * 2);
    float* B1       = (float*)alloc((size_t)n * D * 4); // agg1 output (fp32)
    __half* xh      = (__half*)alloc((size_t)n * D * 2); // x as fp16
    __half* th      = (__half*)alloc((size_t)n * D * 2); // t = h1@W1 as fp16

    int nb4 = (n + 1023) / 1024;           // 4 bins per thread
    int ab = (n + 3) / 4;                  // one wave per node
    int gb = (n + GM - 1) / GM;

    hist_kernel<<<NB, 256, 0, stream>>>(src, dst, x, xh, n * D / 4, pd, ps, E, n);
    colscan_kernel<<<dim3(nb4, Q), 256, 0, stream>>>(pd, ps, qtot_d, qtot_s, n);
    finscan_kernel<<<1, 1024, 0, stream>>>(qtot_d, qtot_s, row_start, norm_src, norm_dst, n);
    fill_kernel<<<NB, 256, 0, stream>>>(src, dst, ew, norm_src, row_start, qtot_d, pd, sorted, E, n);

    // layer 1 agg -> B1; fused [gemm1 + relu + gemm2-matmul] -> th; layer 2 agg + final epilogue -> out
    agg_kernel<0><<<ab, 256, 0, stream>>>(xh, row_start, sorted, B1, nullptr, nullptr, n);
    gemmfused_kernel<<<gb, 256, 0, stream>>>(B1, W0, b0, W1, norm_dst, th, n);
    agg_kernel<1><<<ab, 256, 0, stream>>>(th, row_start, sorted, out, norm_dst, b1, n);
}